// Round 2
// baseline (1695.226 us; speedup 1.0000x reference)
//
#include <hip/hip_runtime.h>
#include <math.h>
#include <stdint.h>

// Problem constants
#define B_   256
#define T_   128
#define NIN_ 1024
#define H1_  512
#define E_   256
#define A_   16
#define MT_  (B_ * T_)   // 32768 rows, t-major: m = t*B_ + b

typedef unsigned short ushort_t;
typedef __attribute__((ext_vector_type(8))) short   short8;
typedef __attribute__((ext_vector_type(8))) __bf16  bf16x8;
typedef __attribute__((ext_vector_type(4))) float   f32x4;

union frag8 { short8 s; bf16x8 b; };

__device__ __forceinline__ ushort_t f2bf(float f) {
  union { float f; unsigned u; } v; v.f = f;
  unsigned r = (v.u + 0x7FFFu + ((v.u >> 16) & 1u)) >> 16;   // RNE
  return (ushort_t)r;
}

// ---------------- workspace layout (bytes) ----------------
// C0 fp32 [T*B][1024] = 128MB at 0 (written late; obs_b bf16 64MB overlays it early)
// chunks of C0 row: [0:256)=Penc(h_enc init) [256:512)=r_pre0 [512:768)=z_pre0 [768:1024)=hn0
static constexpr size_t OFF_C0    = 0;
static constexpr size_t OFF_OBSB  = 0;                      // bf16 [32768][1024], dead after G1
static constexpr size_t OFF_Y     = 134217728;              // fp32 [32768][512] (Y1,Y2)
static constexpr size_t OFF_YG    = 134217728;              // fp32 [32768][256] (after Y2 dead)
static constexpr size_t OFF_XG    = 167772160;              // bf16 [32768][256]
static constexpr size_t OFF_PENCB = 184549376;              // bf16 [32768][256] (after BN2)
static constexpr size_t OFF_XB    = 201326592;              // bf16 [32768][512] (X1,X2)
static constexpr size_t OFF_INN   = 201326592;              // fp32 [32768][256] (after XB dead)
static constexpr size_t OFF_AE    = 234881024;              // fp32 [32768][16]
static constexpr size_t OFF_W1T   = 236978176;              // bf16 [512][1024]
static constexpr size_t OFF_W2T   = 238026752;              // bf16 [512][512]
static constexpr size_t OFF_W3T   = 238551040;              // bf16 [256][512]
static constexpr size_t OFF_WIHT  = 239075328;              // bf16 [768][256]
static constexpr size_t OFF_WHHT  = 239468544;              // bf16 [768][256]
static constexpr size_t OFF_WCT   = 240123904;              // bf16 [1024][256]  (combined W^T)
static constexpr size_t OFF_BSUM  = 241172480;              // fp32 [768]

// ---------------- prologue kernels ----------------

// obs [B,T,NIN] fp32 -> obs_b bf16 t-major [t*B+b][NIN]
__global__ __launch_bounds__(256) void cast_obs_k(const float* __restrict__ obs,
                                                  ushort_t* __restrict__ out) {
  int row_in = blockIdx.x;              // b*T + t
  int b = row_in / T_, t = row_in - b * T_;
  const float4* s4 = (const float4*)(obs + (size_t)row_in * NIN_);
  float4 v = s4[threadIdx.x];
  ushort_t* d = out + (size_t)(t * B_ + b) * NIN_ + threadIdx.x * 4;
  d[0] = f2bf(v.x); d[1] = f2bf(v.y); d[2] = f2bf(v.z); d[3] = f2bf(v.w);
}

// generic fp32 [R,C] -> bf16 [C,R] transpose+cast
__global__ __launch_bounds__(256) void transpose_cast_k(const float* __restrict__ in,
                                                        ushort_t* __restrict__ out,
                                                        int R, int C) {
  __shared__ float tile[32][33];
  int c0 = blockIdx.x * 32, r0 = blockIdx.y * 32;
  int tx = threadIdx.x & 31, ty = threadIdx.x >> 5;   // ty 0..7
  for (int i = 0; i < 4; i++) {
    int r = r0 + ty * 4 + i;
    if (r < R && (c0 + tx) < C) tile[ty * 4 + i][tx] = in[(size_t)r * C + c0 + tx];
  }
  __syncthreads();
  for (int i = 0; i < 4; i++) {
    int c = c0 + ty * 4 + i, r = r0 + tx;
    if (c < C && r < R) out[(size_t)c * R + r] = f2bf(tile[tx][ty * 4 + i]);
  }
}

// Wct rows 0..255: (Whe_h)^T  : Wct[c][k] = Whe[k][c]
__global__ __launch_bounds__(256) void wct_a_k(const float* __restrict__ Whe,
                                               ushort_t* __restrict__ Wct) {
  int c = blockIdx.x, k = threadIdx.x;
  Wct[(size_t)c * 256 + k] = f2bf(Whe[(size_t)k * 256 + c]);
}

// Wct rows 256..1023: (Whe_h @ Whh)^T computed in fp32, one bf16 rounding
__global__ __launch_bounds__(256) void wct_b_k(const float* __restrict__ Whe,
                                               const float* __restrict__ Whh,
                                               ushort_t* __restrict__ Wct) {
  int c = blockIdx.x;   // 0..767 (gh column)
  int k = threadIdx.x;  // h feature
  float acc = 0.f;
  for (int j = 0; j < 256; j++)
    acc += Whe[(size_t)k * 256 + j] * Whh[(size_t)j * 768 + c];
  Wct[(size_t)(256 + c) * 256 + k] = f2bf(acc);
}

__global__ void bsum_k(const float* __restrict__ bih, const float* __restrict__ bhh,
                       float* __restrict__ bs) {
  int i = blockIdx.x * 256 + threadIdx.x;
  if (i < 768) bs[i] = bih[i] + bhh[i];
}

// AE[m=t*B+b][k2] = actions[b,t,:] @ Wae + bae   (fp32)
__global__ __launch_bounds__(256) void ae_k(const float* __restrict__ actions,
                                            const float* __restrict__ Wae,
                                            const float* __restrict__ bae,
                                            float* __restrict__ AE) {
  int idx = blockIdx.x * 256 + threadIdx.x;
  int m = idx >> 4, k2 = idx & 15;
  int t = m >> 8, b = m & 255;
  const float* arow = actions + ((size_t)b * T_ + t) * A_;
  float acc = bae[k2];
  for (int k = 0; k < 16; k++) acc += arow[k] * Wae[k * 16 + k2];
  AE[(size_t)m * 16 + k2] = acc;
}

// Penc[t][b][j] = bhe[j] + (t>0 ? AE[t-1,b,:] @ Whe[256:272,:] : 0)
// writes fp32 into C0 cols [0:256) and bf16 copy to Pencb
__global__ __launch_bounds__(256) void penc_k(const float* __restrict__ AE,
                                              const float* __restrict__ Whe,
                                              const float* __restrict__ bhe,
                                              float* __restrict__ C0,
                                              ushort_t* __restrict__ Pencb) {
  int m = blockIdx.x;          // t*B + b
  int j = threadIdx.x;         // 0..255
  __shared__ float a[16];
  if (threadIdx.x < 16)
    a[threadIdx.x] = (m >= B_) ? AE[(size_t)(m - B_) * 16 + threadIdx.x] : 0.f;
  __syncthreads();
  float acc = bhe[j];
  if (m >= B_) {
    for (int k = 0; k < 16; k++) acc += a[k] * Whe[(size_t)(256 + k) * 256 + j];
  }
  C0[(size_t)m * 1024 + j] = acc;
  Pencb[(size_t)m * 256 + j] = f2bf(acc);
}

// per-t BatchNorm (training, biased var) + ELU, fp32 in -> bf16 out
__global__ __launch_bounds__(512) void bn_elu_k(const float* __restrict__ Y,
                                                const float* __restrict__ g,
                                                const float* __restrict__ be,
                                                ushort_t* __restrict__ Xb) {
  int t = blockIdx.x, f = threadIdx.x;   // 512 features
  const float* base = Y + (size_t)t * B_ * H1_;
  float s = 0.f, ss = 0.f;
  for (int b = 0; b < B_; b++) {
    float v = base[(size_t)b * H1_ + f];
    s += v; ss += v * v;
  }
  float mu  = s * (1.f / B_);
  float var = ss * (1.f / B_) - mu * mu;
  float inv = 1.f / sqrtf(var + 1e-5f);
  float sc = g[f] * inv, sh = be[f] - mu * sc;
  ushort_t* ob = Xb + (size_t)t * B_ * H1_;
  for (int b = 0; b < B_; b++) {
    float v = base[(size_t)b * H1_ + f] * sc + sh;
    float e = v > 0.f ? v : (expf(v) - 1.f);
    ob[(size_t)b * H1_ + f] = f2bf(e);
  }
}

__global__ __launch_bounds__(256) void cast_k(const float* __restrict__ in,
                                              ushort_t* __restrict__ out, long n) {
  long i = (long)blockIdx.x * 256 + threadIdx.x;
  if (i < n) out[i] = f2bf(in[i]);
}

// ---------------- bf16 MFMA GEMM: C[m,n] (+)= A[m,:] . Bt[n,:] + bias[n] ----------------
// A: bf16 [M,lda], Bt: bf16 [N,ldb] (B transposed), C: fp32 (ldc), 64x64 tile, BK=32.
// grid = (M/64, N/64), 256 threads (4 waves in 2x2).
__global__ __launch_bounds__(256) void gemm_bt_k(const ushort_t* __restrict__ A, int lda,
                                                 const ushort_t* __restrict__ Bt, int ldb,
                                                 float* __restrict__ C, int ldc,
                                                 const float* __restrict__ bias,
                                                 int K, int accum) {
  __shared__ __align__(16) ushort_t As[64][40];  // +8 pad: 2-way banks (free)
  __shared__ __align__(16) ushort_t Bs[64][40];
  int tid = threadIdx.x;
  int wave = tid >> 6, lane = tid & 63;
  int q = lane >> 4, l15 = lane & 15;
  int wr = wave >> 1, wc = wave & 1;
  int m0 = blockIdx.x * 64, n0 = blockIdx.y * 64;
  f32x4 acc[2][2] = {};
  int r = tid >> 2, seg = tid & 3;
  const ushort_t* aSrc = A + (size_t)(m0 + r) * lda + seg * 8;
  const ushort_t* bSrc = Bt + (size_t)(n0 + r) * ldb + seg * 8;
  for (int k0 = 0; k0 < K; k0 += 32) {
    *(short8*)&As[r][seg * 8] = *(const short8*)(aSrc + k0);
    *(short8*)&Bs[r][seg * 8] = *(const short8*)(bSrc + k0);
    __syncthreads();
    frag8 a0, a1, b0, b1;
    a0.s = *(const short8*)&As[wr * 32 + l15][q * 8];
    a1.s = *(const short8*)&As[wr * 32 + 16 + l15][q * 8];
    b0.s = *(const short8*)&Bs[wc * 32 + l15][q * 8];
    b1.s = *(const short8*)&Bs[wc * 32 + 16 + l15][q * 8];
    acc[0][0] = __builtin_amdgcn_mfma_f32_16x16x32_bf16(a0.b, b0.b, acc[0][0], 0, 0, 0);
    acc[0][1] = __builtin_amdgcn_mfma_f32_16x16x32_bf16(a0.b, b1.b, acc[0][1], 0, 0, 0);
    acc[1][0] = __builtin_amdgcn_mfma_f32_16x16x32_bf16(a1.b, b0.b, acc[1][0], 0, 0, 0);
    acc[1][1] = __builtin_amdgcn_mfma_f32_16x16x32_bf16(a1.b, b1.b, acc[1][1], 0, 0, 0);
    __syncthreads();
  }
  for (int at = 0; at < 2; at++)
    for (int bt = 0; bt < 2; bt++) {
      int mb = m0 + wr * 32 + at * 16 + q * 4;       // C/D: row = quad*4+i
      int n  = n0 + wc * 32 + bt * 16 + l15;         //      col = lane&15
      float bv = bias ? bias[n] : 0.f;
      for (int i = 0; i < 4; i++) {
        size_t idx = (size_t)(mb + i) * ldc + n;
        float v = acc[at][bt][i] + bv;
        if (accum) v += C[idx];
        C[idx] = v;
      }
    }
}

// ---------------- communication-free GRU recurrence ----------------
// Row partition: block k owns batch rows [16k, 16k+16) for ALL 128 steps.
// h'[b,:] depends only on h[b,:] -> zero inter-block traffic, zero fences.
// 16 blocks x 512 threads (8 waves). Wave w owns h-cols [32w, 32w+32).
// Per wave: 8 output chunks (gate g in {henc,r,z,hn} x colgroup u in {0,1}),
// chunk cols = g*256 + 32w + 16u + l15. Gates for a given h-col are all in
// the same lane -> gate math fully in-register, h_new written to LDS.
// Weights: g=0,1 (henc,r) stationary in VGPRs (128/lane); g=2,3 (z,hn)
// streamed from L2 each step (~256KB/CU-step, L1-path bound ~1.7us/step).
// h double-buffered in LDS; ONE __syncthreads per step; NO global barrier.
__global__ __launch_bounds__(512) void gru_rows_k(
    const ushort_t* __restrict__ Wct,
    const float* __restrict__ C0,
    const float* __restrict__ INN,
    float* __restrict__ outF) {
  __shared__ __align__(16) ushort_t hbuf[2][16][264];   // +8 pad: 2-way banks (free)
  const int tid = threadIdx.x;
  const int w = tid >> 6, lane = tid & 63;
  const int q = lane >> 4, l15 = lane & 15;
  const int r0 = blockIdx.x * 16;          // batch rows [r0, r0+16)
  const int col0 = w * 32;                 // wave's h-col base

  // zero h(0) buffer (both buffers; step0 reads hbuf[0])
  {
    unsigned* hz = (unsigned*)hbuf;
    for (int i = tid; i < 2 * 16 * 264 / 2; i += 512) hz[i] = 0u;
  }

  // stationary weights: gates g=0 (henc), g=1 (r); chunks ch = g*2+u
  frag8 bs[4][8];
#pragma unroll
  for (int g = 0; g < 2; g++)
#pragma unroll
    for (int u = 0; u < 2; u++) {
      const ushort_t* p = Wct + (size_t)(g * 256 + col0 + u * 16 + l15) * 256 + q * 8;
#pragma unroll
      for (int kc = 0; kc < 8; kc++)
        bs[g * 2 + u][kc].s = *(const short8*)(p + kc * 32);
    }
  // streamed weight bases: g=2 (z), g=3 (hn)
  const ushort_t* wz0 = Wct + (size_t)(2 * 256 + col0 + l15) * 256 + q * 8;
  const ushort_t* wz1 = wz0 + (size_t)16 * 256;
  const ushort_t* wn0 = Wct + (size_t)(3 * 256 + col0 + l15) * 256 + q * 8;
  const ushort_t* wn1 = wn0 + (size_t)16 * 256;

  __syncthreads();

  for (int t = 0; t < T_; t++) {
    const int cur = t & 1, nxt = cur ^ 1;
    const float* c0t  = C0  + ((size_t)t * B_ + r0) * 1024;
    const float* innt = INN + ((size_t)t * B_ + r0) * 256;

    // prefetch C0 for stationary gates (henc, r): consumed in epilogue
    float c0he[2][4], c0r[2][4];
#pragma unroll
    for (int u = 0; u < 2; u++) {
      int hc = col0 + u * 16 + l15;
#pragma unroll
      for (int i = 0; i < 4; i++) {
        int row = q * 4 + i;
        c0he[u][i] = c0t[(size_t)row * 1024 + hc];
        c0r[u][i]  = c0t[(size_t)row * 1024 + 256 + hc];
      }
    }

    f32x4 acc[4][2] = {};   // [gate][u]
#pragma unroll
    for (int kc = 0; kc < 8; kc++) {
      frag8 a; a.s = *(const short8*)&hbuf[cur][l15][kc * 32 + q * 8];
      frag8 bz0, bz1, bn0, bn1;
      bz0.s = *(const short8*)(wz0 + kc * 32);
      bz1.s = *(const short8*)(wz1 + kc * 32);
      bn0.s = *(const short8*)(wn0 + kc * 32);
      bn1.s = *(const short8*)(wn1 + kc * 32);
      acc[0][0] = __builtin_amdgcn_mfma_f32_16x16x32_bf16(a.b, bs[0][kc].b, acc[0][0], 0, 0, 0);
      acc[0][1] = __builtin_amdgcn_mfma_f32_16x16x32_bf16(a.b, bs[1][kc].b, acc[0][1], 0, 0, 0);
      acc[1][0] = __builtin_amdgcn_mfma_f32_16x16x32_bf16(a.b, bs[2][kc].b, acc[1][0], 0, 0, 0);
      acc[1][1] = __builtin_amdgcn_mfma_f32_16x16x32_bf16(a.b, bs[3][kc].b, acc[1][1], 0, 0, 0);
      acc[2][0] = __builtin_amdgcn_mfma_f32_16x16x32_bf16(a.b, bz0.b, acc[2][0], 0, 0, 0);
      acc[2][1] = __builtin_amdgcn_mfma_f32_16x16x32_bf16(a.b, bz1.b, acc[2][1], 0, 0, 0);
      acc[3][0] = __builtin_amdgcn_mfma_f32_16x16x32_bf16(a.b, bn0.b, acc[3][0], 0, 0, 0);
      acc[3][1] = __builtin_amdgcn_mfma_f32_16x16x32_bf16(a.b, bn1.b, acc[3][1], 0, 0, 0);
    }

    // epilogue: remaining C0 (z, hn) + INN loaded here (one wait, overlapped across waves)
#pragma unroll
    for (int u = 0; u < 2; u++) {
      int hc = col0 + u * 16 + l15;
#pragma unroll
      for (int i = 0; i < 4; i++) {
        int row = q * 4 + i;
        float zc = c0t[(size_t)row * 1024 + 512 + hc];
        float nc = c0t[(size_t)row * 1024 + 768 + hc];
        float ic = innt[(size_t)row * 256 + hc];
        float henc = acc[0][u][i] + c0he[u][i];
        float rp   = acc[1][u][i] + c0r[u][i];
        float zp   = acc[2][u][i] + zc;
        float hn   = acc[3][u][i] + nc;
        float rg = 1.f / (1.f + expf(-rp));
        float zg = 1.f / (1.f + expf(-zp));
        float ng = tanhf(ic + rg * hn);
        float hv = (1.f - zg) * ng + zg * henc;
        if (t < T_ - 1) hbuf[nxt][row][hc] = f2bf(hv);
        else            outF[(size_t)(r0 + row) * 256 + hc] = hv;
      }
    }
    __syncthreads();   // h(t+1) complete before any wave reads it; also keeps
                       // buffer reuse safe (writes to hbuf[cur] happen next step)
  }
}

// ---------------- launch ----------------
extern "C" void kernel_launch(void* const* d_in, const int* in_sizes, int n_in,
                              void* d_out, int out_size, void* d_ws, size_t ws_size,
                              hipStream_t stream) {
  const float* obs     = (const float*)d_in[0];
  const float* actions = (const float*)d_in[1];
  const float* W1  = (const float*)d_in[2];
  const float* b1  = (const float*)d_in[3];
  const float* g1  = (const float*)d_in[4];
  const float* be1 = (const float*)d_in[5];
  const float* W2  = (const float*)d_in[6];
  const float* b2  = (const float*)d_in[7];
  const float* g2  = (const float*)d_in[8];
  const float* be2 = (const float*)d_in[9];
  const float* W3  = (const float*)d_in[10];
  const float* b3  = (const float*)d_in[11];
  const float* Wih = (const float*)d_in[12];
  const float* bih = (const float*)d_in[13];
  const float* Whh = (const float*)d_in[14];
  const float* bhh = (const float*)d_in[15];
  const float* Whe = (const float*)d_in[16];
  const float* bhe = (const float*)d_in[17];
  const float* Wae = (const float*)d_in[18];
  const float* bae = (const float*)d_in[19];

  char* ws = (char*)d_ws;
  float*    C0    = (float*)(ws + OFF_C0);
  ushort_t* obsb  = (ushort_t*)(ws + OFF_OBSB);
  float*    Y     = (float*)(ws + OFF_Y);
  float*    Yg    = (float*)(ws + OFF_YG);
  ushort_t* XG    = (ushort_t*)(ws + OFF_XG);
  ushort_t* Pencb = (ushort_t*)(ws + OFF_PENCB);
  ushort_t* Xb    = (ushort_t*)(ws + OFF_XB);
  float*    INN   = (float*)(ws + OFF_INN);
  float*    AE    = (float*)(ws + OFF_AE);
  ushort_t* W1t   = (ushort_t*)(ws + OFF_W1T);
  ushort_t* W2t   = (ushort_t*)(ws + OFF_W2T);
  ushort_t* W3t   = (ushort_t*)(ws + OFF_W3T);
  ushort_t* Wiht  = (ushort_t*)(ws + OFF_WIHT);
  ushort_t* Whht  = (ushort_t*)(ws + OFF_WHHT);
  ushort_t* Wct   = (ushort_t*)(ws + OFF_WCT);
  float*    bsum  = (float*)(ws + OFF_BSUM);
  float*    outF  = (float*)d_out;

  // prologue: casts / transposes / small precomputes
  cast_obs_k<<<MT_, 256, 0, stream>>>(obs, obsb);
  transpose_cast_k<<<dim3(16, 32), 256, 0, stream>>>(W1, W1t, 1024, 512);
  transpose_cast_k<<<dim3(16, 16), 256, 0, stream>>>(W2, W2t, 512, 512);
  transpose_cast_k<<<dim3(8, 16),  256, 0, stream>>>(W3, W3t, 512, 256);
  transpose_cast_k<<<dim3(24, 8),  256, 0, stream>>>(Wih, Wiht, 256, 768);
  transpose_cast_k<<<dim3(24, 8),  256, 0, stream>>>(Whh, Whht, 256, 768);
  wct_a_k<<<256, 256, 0, stream>>>(Whe, Wct);
  wct_b_k<<<768, 256, 0, stream>>>(Whe, Whh, Wct);
  bsum_k<<<3, 256, 0, stream>>>(bih, bhh, bsum);
  ae_k<<<MT_ * 16 / 256, 256, 0, stream>>>(actions, Wae, bae, AE);

  // MLP (parallel over all T*B rows, t-major)
  gemm_bt_k<<<dim3(512, 8), 256, 0, stream>>>(obsb, 1024, W1t, 1024, Y, 512, b1, 1024, 0);
  bn_elu_k<<<T_, 512, 0, stream>>>(Y, g1, be1, Xb);
  gemm_bt_k<<<dim3(512, 8), 256, 0, stream>>>(Xb, 512, W2t, 512, Y, 512, b2, 512, 0);
  bn_elu_k<<<T_, 512, 0, stream>>>(Y, g2, be2, Xb);
  gemm_bt_k<<<dim3(512, 4), 256, 0, stream>>>(Xb, 512, W3t, 512, Yg, 256, b3, 512, 0);
  cast_k<<<MT_ * 256 / 256, 256, 0, stream>>>(Yg, XG, (long)MT_ * 256);

  // per-step constants: Penc -> C0[:,0:256); r/z pre -> C0[:,256:768); hn0 -> C0[:,768:1024); INN
  penc_k<<<MT_, 256, 0, stream>>>(AE, Whe, bhe, C0, Pencb);
  gemm_bt_k<<<dim3(512, 8), 256, 0, stream>>>(XG, 256, Wiht, 256, C0 + 256, 1024, bsum, 256, 0);
  gemm_bt_k<<<dim3(512, 8), 256, 0, stream>>>(Pencb, 256, Whht, 256, C0 + 256, 1024, nullptr, 256, 1);
  gemm_bt_k<<<dim3(512, 4), 256, 0, stream>>>(Pencb, 256, Whht + 512 * 256, 256, C0 + 768, 1024, bhh + 512, 256, 0);
  gemm_bt_k<<<dim3(512, 4), 256, 0, stream>>>(XG, 256, Wiht + 512 * 256, 256, INN, 256, bih + 512, 256, 0);

  // sequential recurrence: 16 independent blocks, each owns 16 batch rows for
  // all 128 steps; h stays in LDS; no inter-block sync of any kind.
  gru_rows_k<<<16, 512, 0, stream>>>(Wct, C0, INN, outF);
}

// Round 3
// 1325.065 us; speedup vs baseline: 1.2794x; 1.2794x over previous
//
#include <hip/hip_runtime.h>
#include <math.h>
#include <stdint.h>

// Problem constants
#define B_   256
#define T_   128
#define NIN_ 1024
#define H1_  512
#define E_   256
#define A_   16
#define MT_  (B_ * T_)   // 32768 rows, t-major: m = t*B_ + b

typedef unsigned short ushort_t;
typedef __attribute__((ext_vector_type(8))) short   short8;
typedef __attribute__((ext_vector_type(8))) __bf16  bf16x8;
typedef __attribute__((ext_vector_type(4))) float   f32x4;

union frag8 { short8 s; bf16x8 b; };

__device__ __forceinline__ ushort_t f2bf(float f) {
  union { float f; unsigned u; } v; v.f = f;
  unsigned r = (v.u + 0x7FFFu + ((v.u >> 16) & 1u)) >> 16;   // RNE
  return (ushort_t)r;
}

// ---------------- workspace layout (bytes) ----------------
// C0 fp32 [T*B][1024] = 128MB at 0 (written late; obs_b bf16 64MB overlays it early)
// chunks of C0 row: [0:256)=Penc(h_enc init) [256:512)=r_pre0 [512:768)=z_pre0 [768:1024)=hn0
static constexpr size_t OFF_C0    = 0;
static constexpr size_t OFF_OBSB  = 0;                      // bf16 [32768][1024], dead after G1
static constexpr size_t OFF_Y     = 134217728;              // fp32 [32768][512] (Y1,Y2)
static constexpr size_t OFF_YG    = 134217728;              // fp32 [32768][256] (after Y2 dead)
static constexpr size_t OFF_XG    = 167772160;              // bf16 [32768][256]
static constexpr size_t OFF_PENCB = 184549376;              // bf16 [32768][256] (after BN2)
static constexpr size_t OFF_XB    = 201326592;              // bf16 [32768][512] (X1,X2)
static constexpr size_t OFF_INN   = 201326592;              // fp32 [32768][256] (after XB dead)
static constexpr size_t OFF_AE    = 234881024;              // fp32 [32768][16]
static constexpr size_t OFF_W1T   = 236978176;              // bf16 [512][1024]
static constexpr size_t OFF_W2T   = 238026752;              // bf16 [512][512]
static constexpr size_t OFF_W3T   = 238551040;              // bf16 [256][512]
static constexpr size_t OFF_WIHT  = 239075328;              // bf16 [768][256]
static constexpr size_t OFF_WHHT  = 239468544;              // bf16 [768][256]
static constexpr size_t OFF_WCT   = 240123904;              // bf16 [1024][256]  (combined W^T)
static constexpr size_t OFF_BSUM  = 241172480;              // fp32 [768]

// ---------------- prologue kernels ----------------

// obs [B,T,NIN] fp32 -> obs_b bf16 t-major [t*B+b][NIN]
__global__ __launch_bounds__(256) void cast_obs_k(const float* __restrict__ obs,
                                                  ushort_t* __restrict__ out) {
  int row_in = blockIdx.x;              // b*T + t
  int b = row_in / T_, t = row_in - b * T_;
  const float4* s4 = (const float4*)(obs + (size_t)row_in * NIN_);
  float4 v = s4[threadIdx.x];
  ushort_t* d = out + (size_t)(t * B_ + b) * NIN_ + threadIdx.x * 4;
  d[0] = f2bf(v.x); d[1] = f2bf(v.y); d[2] = f2bf(v.z); d[3] = f2bf(v.w);
}

// generic fp32 [R,C] -> bf16 [C,R] transpose+cast
__global__ __launch_bounds__(256) void transpose_cast_k(const float* __restrict__ in,
                                                        ushort_t* __restrict__ out,
                                                        int R, int C) {
  __shared__ float tile[32][33];
  int c0 = blockIdx.x * 32, r0 = blockIdx.y * 32;
  int tx = threadIdx.x & 31, ty = threadIdx.x >> 5;   // ty 0..7
  for (int i = 0; i < 4; i++) {
    int r = r0 + ty * 4 + i;
    if (r < R && (c0 + tx) < C) tile[ty * 4 + i][tx] = in[(size_t)r * C + c0 + tx];
  }
  __syncthreads();
  for (int i = 0; i < 4; i++) {
    int c = c0 + ty * 4 + i, r = r0 + tx;
    if (c < C && r < R) out[(size_t)c * R + r] = f2bf(tile[tx][ty * 4 + i]);
  }
}

// Wct rows 0..255: (Whe_h)^T  : Wct[c][k] = Whe[k][c]
__global__ __launch_bounds__(256) void wct_a_k(const float* __restrict__ Whe,
                                               ushort_t* __restrict__ Wct) {
  int c = blockIdx.x, k = threadIdx.x;
  Wct[(size_t)c * 256 + k] = f2bf(Whe[(size_t)k * 256 + c]);
}

// Wct rows 256..1023: (Whe_h @ Whh)^T computed in fp32, one bf16 rounding
__global__ __launch_bounds__(256) void wct_b_k(const float* __restrict__ Whe,
                                               const float* __restrict__ Whh,
                                               ushort_t* __restrict__ Wct) {
  int c = blockIdx.x;   // 0..767 (gh column)
  int k = threadIdx.x;  // h feature
  float acc = 0.f;
  for (int j = 0; j < 256; j++)
    acc += Whe[(size_t)k * 256 + j] * Whh[(size_t)j * 768 + c];
  Wct[(size_t)(256 + c) * 256 + k] = f2bf(acc);
}

__global__ void bsum_k(const float* __restrict__ bih, const float* __restrict__ bhh,
                       float* __restrict__ bs) {
  int i = blockIdx.x * 256 + threadIdx.x;
  if (i < 768) bs[i] = bih[i] + bhh[i];
}

// AE[m=t*B+b][k2] = actions[b,t,:] @ Wae + bae   (fp32)
__global__ __launch_bounds__(256) void ae_k(const float* __restrict__ actions,
                                            const float* __restrict__ Wae,
                                            const float* __restrict__ bae,
                                            float* __restrict__ AE) {
  int idx = blockIdx.x * 256 + threadIdx.x;
  int m = idx >> 4, k2 = idx & 15;
  int t = m >> 8, b = m & 255;
  const float* arow = actions + ((size_t)b * T_ + t) * A_;
  float acc = bae[k2];
  for (int k = 0; k < 16; k++) acc += arow[k] * Wae[k * 16 + k2];
  AE[(size_t)m * 16 + k2] = acc;
}

// Penc[t][b][j] = bhe[j] + (t>0 ? AE[t-1,b,:] @ Whe[256:272,:] : 0)
// writes fp32 into C0 cols [0:256) and bf16 copy to Pencb
__global__ __launch_bounds__(256) void penc_k(const float* __restrict__ AE,
                                              const float* __restrict__ Whe,
                                              const float* __restrict__ bhe,
                                              float* __restrict__ C0,
                                              ushort_t* __restrict__ Pencb) {
  int m = blockIdx.x;          // t*B + b
  int j = threadIdx.x;         // 0..255
  __shared__ float a[16];
  if (threadIdx.x < 16)
    a[threadIdx.x] = (m >= B_) ? AE[(size_t)(m - B_) * 16 + threadIdx.x] : 0.f;
  __syncthreads();
  float acc = bhe[j];
  if (m >= B_) {
    for (int k = 0; k < 16; k++) acc += a[k] * Whe[(size_t)(256 + k) * 256 + j];
  }
  C0[(size_t)m * 1024 + j] = acc;
  Pencb[(size_t)m * 256 + j] = f2bf(acc);
}

// per-t BatchNorm (training, biased var) + ELU, fp32 in -> bf16 out
__global__ __launch_bounds__(512) void bn_elu_k(const float* __restrict__ Y,
                                                const float* __restrict__ g,
                                                const float* __restrict__ be,
                                                ushort_t* __restrict__ Xb) {
  int t = blockIdx.x, f = threadIdx.x;   // 512 features
  const float* base = Y + (size_t)t * B_ * H1_;
  float s = 0.f, ss = 0.f;
  for (int b = 0; b < B_; b++) {
    float v = base[(size_t)b * H1_ + f];
    s += v; ss += v * v;
  }
  float mu  = s * (1.f / B_);
  float var = ss * (1.f / B_) - mu * mu;
  float inv = 1.f / sqrtf(var + 1e-5f);
  float sc = g[f] * inv, sh = be[f] - mu * sc;
  ushort_t* ob = Xb + (size_t)t * B_ * H1_;
  for (int b = 0; b < B_; b++) {
    float v = base[(size_t)b * H1_ + f] * sc + sh;
    float e = v > 0.f ? v : (expf(v) - 1.f);
    ob[(size_t)b * H1_ + f] = f2bf(e);
  }
}

__global__ __launch_bounds__(256) void cast_k(const float* __restrict__ in,
                                              ushort_t* __restrict__ out, long n) {
  long i = (long)blockIdx.x * 256 + threadIdx.x;
  if (i < n) out[i] = f2bf(in[i]);
}

// ---------------- bf16 MFMA GEMM: C[m,n] (+)= A[m,:] . Bt[n,:] + bias[n] ----------------
// A: bf16 [M,lda], Bt: bf16 [N,ldb] (B transposed), C: fp32 (ldc), 64x64 tile, BK=32.
// grid = (M/64, N/64), 256 threads (4 waves in 2x2).
__global__ __launch_bounds__(256) void gemm_bt_k(const ushort_t* __restrict__ A, int lda,
                                                 const ushort_t* __restrict__ Bt, int ldb,
                                                 float* __restrict__ C, int ldc,
                                                 const float* __restrict__ bias,
                                                 int K, int accum) {
  __shared__ __align__(16) ushort_t As[64][40];  // +8 pad: 2-way banks (free)
  __shared__ __align__(16) ushort_t Bs[64][40];
  int tid = threadIdx.x;
  int wave = tid >> 6, lane = tid & 63;
  int q = lane >> 4, l15 = lane & 15;
  int wr = wave >> 1, wc = wave & 1;
  int m0 = blockIdx.x * 64, n0 = blockIdx.y * 64;
  f32x4 acc[2][2] = {};
  int r = tid >> 2, seg = tid & 3;
  const ushort_t* aSrc = A + (size_t)(m0 + r) * lda + seg * 8;
  const ushort_t* bSrc = Bt + (size_t)(n0 + r) * ldb + seg * 8;
  for (int k0 = 0; k0 < K; k0 += 32) {
    *(short8*)&As[r][seg * 8] = *(const short8*)(aSrc + k0);
    *(short8*)&Bs[r][seg * 8] = *(const short8*)(bSrc + k0);
    __syncthreads();
    frag8 a0, a1, b0, b1;
    a0.s = *(const short8*)&As[wr * 32 + l15][q * 8];
    a1.s = *(const short8*)&As[wr * 32 + 16 + l15][q * 8];
    b0.s = *(const short8*)&Bs[wc * 32 + l15][q * 8];
    b1.s = *(const short8*)&Bs[wc * 32 + 16 + l15][q * 8];
    acc[0][0] = __builtin_amdgcn_mfma_f32_16x16x32_bf16(a0.b, b0.b, acc[0][0], 0, 0, 0);
    acc[0][1] = __builtin_amdgcn_mfma_f32_16x16x32_bf16(a0.b, b1.b, acc[0][1], 0, 0, 0);
    acc[1][0] = __builtin_amdgcn_mfma_f32_16x16x32_bf16(a1.b, b0.b, acc[1][0], 0, 0, 0);
    acc[1][1] = __builtin_amdgcn_mfma_f32_16x16x32_bf16(a1.b, b1.b, acc[1][1], 0, 0, 0);
    __syncthreads();
  }
  for (int at = 0; at < 2; at++)
    for (int bt = 0; bt < 2; bt++) {
      int mb = m0 + wr * 32 + at * 16 + q * 4;       // C/D: row = quad*4+i
      int n  = n0 + wc * 32 + bt * 16 + l15;         //      col = lane&15
      float bv = bias ? bias[n] : 0.f;
      for (int i = 0; i < 4; i++) {
        size_t idx = (size_t)(mb + i) * ldc + n;
        float v = acc[at][bt][i] + bv;
        if (accum) v += C[idx];
        C[idx] = v;
      }
    }
}

// ---------------- communication-free GRU recurrence (v3) ----------------
// Row partition: block k owns batch rows [16k,16k+16) for ALL 128 steps; no
// inter-block communication. 16 blocks x 512 threads (8 waves, 2/SIMD).
// Weight residency sized to actual HW budgets (v2 post-mortem: VGPR=128 proved
// the compiler demoted "stationary" weights; need total <= 256 VGPR):
//   - hn gate weights (128KB)  -> LDS-resident [256][264] (pad: 2-way, free)
//   - henc gate weights        -> VGPR-stationary (64 VGPR/lane)
//   - r+z gate weights (256KB) -> streamed from L2 each step (irreducible:
//     512KB total > on-chip capacity; ~4000cy/step at 64B/cy)
//   - ALL C0/INN dwords (40/lane) prefetched at step top, consumed in epilogue
//     -> HBM latency overlaps MFMA+stream phase instead of serializing.
// VGPR budget: 64 wts + 32 acc + 40 prefetch + ~60 frags/addr ~= 210 < 256.
__global__ __launch_bounds__(512, 1) void gru_rows_k(
    const ushort_t* __restrict__ Wct,
    const float* __restrict__ C0,
    const float* __restrict__ INN,
    float* __restrict__ outF) {
  __shared__ __align__(16) ushort_t Wn[256][264];       // hn weights (135KB)
  __shared__ __align__(16) ushort_t hbuf[2][16][264];   // h double-buffer (17KB)
  const int tid = threadIdx.x;
  const int w = tid >> 6, lane = tid & 63;
  const int q = lane >> 4, l15 = lane & 15;
  const int r0 = blockIdx.x * 16;          // batch rows [r0, r0+16)
  const int col0 = w * 32;                 // wave's h-col base

  // zero h(0)
  {
    unsigned* hz = (unsigned*)hbuf;
    for (int i = tid; i < 2 * 16 * 264 / 2; i += 512) hz[i] = 0u;
  }
  // stage hn weights (Wct rows 768..1023) into LDS
  for (int i = tid; i < 256 * 32; i += 512) {
    int rr = i >> 5, ss = i & 31;
    *(short8*)&Wn[rr][ss * 8] = *(const short8*)(Wct + (size_t)(768 + rr) * 256 + ss * 8);
  }

  // VGPR-stationary henc weights (Wct rows 0..255): 2u x 8kc = 64 VGPR
  frag8 whe_s[2][8];
#pragma unroll
  for (int u = 0; u < 2; u++) {
    const ushort_t* p = Wct + (size_t)(col0 + u * 16 + l15) * 256 + q * 8;
#pragma unroll
    for (int kc = 0; kc < 8; kc++) whe_s[u][kc].s = *(const short8*)(p + kc * 32);
  }
  // streamed bases: r (rows 256+), z (rows 512+)
  const ushort_t* wr0 = Wct + (size_t)(256 + col0 + l15) * 256 + q * 8;
  const ushort_t* wr1 = wr0 + (size_t)16 * 256;
  const ushort_t* wz0 = Wct + (size_t)(512 + col0 + l15) * 256 + q * 8;
  const ushort_t* wz1 = wz0 + (size_t)16 * 256;

  __syncthreads();

  for (int t = 0; t < T_; t++) {
    const int cur = t & 1, nxt = cur ^ 1;
    const float* c0t  = C0  + ((size_t)t * B_ + r0) * 1024;
    const float* innt = INN + ((size_t)t * B_ + r0) * 256;

    // prefetch ALL per-step C0/INN (40 dwords/lane), consumed in epilogue
    float c0g[4][2][4], innv[2][4];
#pragma unroll
    for (int u = 0; u < 2; u++) {
      int hc = col0 + u * 16 + l15;
#pragma unroll
      for (int i = 0; i < 4; i++) {
        int row = q * 4 + i;
        const float* rp = c0t + (size_t)row * 1024 + hc;
        c0g[0][u][i] = rp[0];
        c0g[1][u][i] = rp[256];
        c0g[2][u][i] = rp[512];
        c0g[3][u][i] = rp[768];
        innv[u][i] = innt[(size_t)row * 256 + hc];
      }
    }

    f32x4 acc[4][2] = {};   // [gate][u]
#pragma unroll
    for (int kc = 0; kc < 8; kc++) {
      frag8 a; a.s = *(const short8*)&hbuf[cur][l15][kc * 32 + q * 8];
      frag8 br0_, br1_, bz0_, bz1_, bn0_, bn1_;
      br0_.s = *(const short8*)(wr0 + kc * 32);
      br1_.s = *(const short8*)(wr1 + kc * 32);
      bz0_.s = *(const short8*)(wz0 + kc * 32);
      bz1_.s = *(const short8*)(wz1 + kc * 32);
      bn0_.s = *(const short8*)&Wn[col0 + l15][kc * 32 + q * 8];
      bn1_.s = *(const short8*)&Wn[col0 + 16 + l15][kc * 32 + q * 8];
      acc[0][0] = __builtin_amdgcn_mfma_f32_16x16x32_bf16(a.b, whe_s[0][kc].b, acc[0][0], 0, 0, 0);
      acc[0][1] = __builtin_amdgcn_mfma_f32_16x16x32_bf16(a.b, whe_s[1][kc].b, acc[0][1], 0, 0, 0);
      acc[1][0] = __builtin_amdgcn_mfma_f32_16x16x32_bf16(a.b, br0_.b, acc[1][0], 0, 0, 0);
      acc[1][1] = __builtin_amdgcn_mfma_f32_16x16x32_bf16(a.b, br1_.b, acc[1][1], 0, 0, 0);
      acc[2][0] = __builtin_amdgcn_mfma_f32_16x16x32_bf16(a.b, bz0_.b, acc[2][0], 0, 0, 0);
      acc[2][1] = __builtin_amdgcn_mfma_f32_16x16x32_bf16(a.b, bz1_.b, acc[2][1], 0, 0, 0);
      acc[3][0] = __builtin_amdgcn_mfma_f32_16x16x32_bf16(a.b, bn0_.b, acc[3][0], 0, 0, 0);
      acc[3][1] = __builtin_amdgcn_mfma_f32_16x16x32_bf16(a.b, bn1_.b, acc[3][1], 0, 0, 0);
    }

    // epilogue: gate math on prefetched values, write h(t+1) to LDS
#pragma unroll
    for (int u = 0; u < 2; u++) {
      int hc = col0 + u * 16 + l15;
#pragma unroll
      for (int i = 0; i < 4; i++) {
        int row = q * 4 + i;
        float henc = acc[0][u][i] + c0g[0][u][i];
        float rp   = acc[1][u][i] + c0g[1][u][i];
        float zp   = acc[2][u][i] + c0g[2][u][i];
        float hn   = acc[3][u][i] + c0g[3][u][i];
        float rg = 1.f / (1.f + expf(-rp));
        float zg = 1.f / (1.f + expf(-zp));
        float ng = tanhf(innv[u][i] + rg * hn);
        float hv = (1.f - zg) * ng + zg * henc;
        if (t < T_ - 1) hbuf[nxt][row][hc] = f2bf(hv);
        else            outF[(size_t)(r0 + row) * 256 + hc] = hv;
      }
    }
    __syncthreads();   // h(t+1) complete before any wave reads it next step
  }
}

// ---------------- launch ----------------
extern "C" void kernel_launch(void* const* d_in, const int* in_sizes, int n_in,
                              void* d_out, int out_size, void* d_ws, size_t ws_size,
                              hipStream_t stream) {
  const float* obs     = (const float*)d_in[0];
  const float* actions = (const float*)d_in[1];
  const float* W1  = (const float*)d_in[2];
  const float* b1  = (const float*)d_in[3];
  const float* g1  = (const float*)d_in[4];
  const float* be1 = (const float*)d_in[5];
  const float* W2  = (const float*)d_in[6];
  const float* b2  = (const float*)d_in[7];
  const float* g2  = (const float*)d_in[8];
  const float* be2 = (const float*)d_in[9];
  const float* W3  = (const float*)d_in[10];
  const float* b3  = (const float*)d_in[11];
  const float* Wih = (const float*)d_in[12];
  const float* bih = (const float*)d_in[13];
  const float* Whh = (const float*)d_in[14];
  const float* bhh = (const float*)d_in[15];
  const float* Whe = (const float*)d_in[16];
  const float* bhe = (const float*)d_in[17];
  const float* Wae = (const float*)d_in[18];
  const float* bae = (const float*)d_in[19];

  char* ws = (char*)d_ws;
  float*    C0    = (float*)(ws + OFF_C0);
  ushort_t* obsb  = (ushort_t*)(ws + OFF_OBSB);
  float*    Y     = (float*)(ws + OFF_Y);
  float*    Yg    = (float*)(ws + OFF_YG);
  ushort_t* XG    = (ushort_t*)(ws + OFF_XG);
  ushort_t* Pencb = (ushort_t*)(ws + OFF_PENCB);
  ushort_t* Xb    = (ushort_t*)(ws + OFF_XB);
  float*    INN   = (float*)(ws + OFF_INN);
  float*    AE    = (float*)(ws + OFF_AE);
  ushort_t* W1t   = (ushort_t*)(ws + OFF_W1T);
  ushort_t* W2t   = (ushort_t*)(ws + OFF_W2T);
  ushort_t* W3t   = (ushort_t*)(ws + OFF_W3T);
  ushort_t* Wiht  = (ushort_t*)(ws + OFF_WIHT);
  ushort_t* Whht  = (ushort_t*)(ws + OFF_WHHT);
  ushort_t* Wct   = (ushort_t*)(ws + OFF_WCT);
  float*    bsum  = (float*)(ws + OFF_BSUM);
  float*    outF  = (float*)d_out;

  // prologue: casts / transposes / small precomputes
  cast_obs_k<<<MT_, 256, 0, stream>>>(obs, obsb);
  transpose_cast_k<<<dim3(16, 32), 256, 0, stream>>>(W1, W1t, 1024, 512);
  transpose_cast_k<<<dim3(16, 16), 256, 0, stream>>>(W2, W2t, 512, 512);
  transpose_cast_k<<<dim3(8, 16),  256, 0, stream>>>(W3, W3t, 512, 256);
  transpose_cast_k<<<dim3(24, 8),  256, 0, stream>>>(Wih, Wiht, 256, 768);
  transpose_cast_k<<<dim3(24, 8),  256, 0, stream>>>(Whh, Whht, 256, 768);
  wct_a_k<<<256, 256, 0, stream>>>(Whe, Wct);
  wct_b_k<<<768, 256, 0, stream>>>(Whe, Whh, Wct);
  bsum_k<<<3, 256, 0, stream>>>(bih, bhh, bsum);
  ae_k<<<MT_ * 16 / 256, 256, 0, stream>>>(actions, Wae, bae, AE);

  // MLP (parallel over all T*B rows, t-major)
  gemm_bt_k<<<dim3(512, 8), 256, 0, stream>>>(obsb, 1024, W1t, 1024, Y, 512, b1, 1024, 0);
  bn_elu_k<<<T_, 512, 0, stream>>>(Y, g1, be1, Xb);
  gemm_bt_k<<<dim3(512, 8), 256, 0, stream>>>(Xb, 512, W2t, 512, Y, 512, b2, 512, 0);
  bn_elu_k<<<T_, 512, 0, stream>>>(Y, g2, be2, Xb);
  gemm_bt_k<<<dim3(512, 4), 256, 0, stream>>>(Xb, 512, W3t, 512, Yg, 256, b3, 512, 0);
  cast_k<<<MT_ * 256 / 256, 256, 0, stream>>>(Yg, XG, (long)MT_ * 256);

  // per-step constants: Penc -> C0[:,0:256); r/z pre -> C0[:,256:768); hn0 -> C0[:,768:1024); INN
  penc_k<<<MT_, 256, 0, stream>>>(AE, Whe, bhe, C0, Pencb);
  gemm_bt_k<<<dim3(512, 8), 256, 0, stream>>>(XG, 256, Wiht, 256, C0 + 256, 1024, bsum, 256, 0);
  gemm_bt_k<<<dim3(512, 8), 256, 0, stream>>>(Pencb, 256, Whht, 256, C0 + 256, 1024, nullptr, 256, 1);
  gemm_bt_k<<<dim3(512, 4), 256, 0, stream>>>(Pencb, 256, Whht + 512 * 256, 256, C0 + 768, 1024, bhh + 512, 256, 0);
  gemm_bt_k<<<dim3(512, 4), 256, 0, stream>>>(XG, 256, Wiht + 512 * 256, 256, INN, 256, bih + 512, 256, 0);

  // sequential recurrence: 16 independent blocks, each owns 16 batch rows for
  // all 128 steps; h stays in LDS; no inter-block sync of any kind.
  gru_rows_k<<<16, 512, 0, stream>>>(Wct, C0, INN, outF);
}

// Round 5
// 1318.538 us; speedup vs baseline: 1.2857x; 1.0049x over previous
//
#include <hip/hip_runtime.h>
#include <math.h>
#include <stdint.h>

// Problem constants
#define B_   256
#define T_   128
#define NIN_ 1024
#define H1_  512
#define E_   256
#define A_   16
#define MT_  (B_ * T_)   // 32768 rows, t-major: m = t*B_ + b

typedef unsigned short ushort_t;
typedef __attribute__((ext_vector_type(8))) short   short8;
typedef __attribute__((ext_vector_type(8))) __bf16  bf16x8;
typedef __attribute__((ext_vector_type(4))) float   f32x4;

union frag8 { short8 s; bf16x8 b; };

__device__ __forceinline__ ushort_t f2bf(float f) {
  union { float f; unsigned u; } v; v.f = f;
  unsigned r = (v.u + 0x7FFFu + ((v.u >> 16) & 1u)) >> 16;   // RNE
  return (ushort_t)r;
}

// ---------------- workspace layout (bytes) ----------------
// C0 fp32 [T*B][1024] = 128MB at 0 (written late; obs_b bf16 64MB overlays it early)
// chunks of C0 row: [0:256)=Penc(h_enc init) [256:512)=r_pre0 [512:768)=z_pre0 [768:1024)=hn0
static constexpr size_t OFF_C0    = 0;
static constexpr size_t OFF_OBSB  = 0;                      // bf16 [32768][1024], dead after G1
static constexpr size_t OFF_Y     = 134217728;              // fp32 [32768][512] (Y1,Y2)
static constexpr size_t OFF_YG    = 134217728;              // fp32 [32768][256] (after Y2 dead)
static constexpr size_t OFF_XG    = 167772160;              // bf16 [32768][256]
static constexpr size_t OFF_PENCB = 184549376;              // bf16 [32768][256] (after BN2)
static constexpr size_t OFF_XB    = 201326592;              // bf16 [32768][512] (X1,X2)
static constexpr size_t OFF_INN   = 201326592;              // fp32 [32768][256] (after XB dead)
static constexpr size_t OFF_AE    = 234881024;              // fp32 [32768][16]
static constexpr size_t OFF_W1T   = 236978176;              // bf16 [512][1024]
static constexpr size_t OFF_W2T   = 238026752;              // bf16 [512][512]
static constexpr size_t OFF_W3T   = 238551040;              // bf16 [256][512]
static constexpr size_t OFF_WIHT  = 239075328;              // bf16 [768][256]
static constexpr size_t OFF_WHHT  = 239468544;              // bf16 [768][256]
static constexpr size_t OFF_WCT   = 240123904;              // bf16 [1024][256]  (combined W^T)
static constexpr size_t OFF_BSUM  = 241172480;              // fp32 [768]

// ---------------- prologue kernels ----------------

// obs [B,T,NIN] fp32 -> obs_b bf16 t-major [t*B+b][NIN]
__global__ __launch_bounds__(256) void cast_obs_k(const float* __restrict__ obs,
                                                  ushort_t* __restrict__ out) {
  int row_in = blockIdx.x;              // b*T + t
  int b = row_in / T_, t = row_in - b * T_;
  const float4* s4 = (const float4*)(obs + (size_t)row_in * NIN_);
  float4 v = s4[threadIdx.x];
  ushort_t* d = out + (size_t)(t * B_ + b) * NIN_ + threadIdx.x * 4;
  d[0] = f2bf(v.x); d[1] = f2bf(v.y); d[2] = f2bf(v.z); d[3] = f2bf(v.w);
}

// generic fp32 [R,C] -> bf16 [C,R] transpose+cast
__global__ __launch_bounds__(256) void transpose_cast_k(const float* __restrict__ in,
                                                        ushort_t* __restrict__ out,
                                                        int R, int C) {
  __shared__ float tile[32][33];
  int c0 = blockIdx.x * 32, r0 = blockIdx.y * 32;
  int tx = threadIdx.x & 31, ty = threadIdx.x >> 5;   // ty 0..7
  for (int i = 0; i < 4; i++) {
    int r = r0 + ty * 4 + i;
    if (r < R && (c0 + tx) < C) tile[ty * 4 + i][tx] = in[(size_t)r * C + c0 + tx];
  }
  __syncthreads();
  for (int i = 0; i < 4; i++) {
    int c = c0 + ty * 4 + i, r = r0 + tx;
    if (c < C && r < R) out[(size_t)c * R + r] = f2bf(tile[tx][ty * 4 + i]);
  }
}

// Wct rows 0..255: (Whe_h)^T  : Wct[c][k] = Whe[k][c]
__global__ __launch_bounds__(256) void wct_a_k(const float* __restrict__ Whe,
                                               ushort_t* __restrict__ Wct) {
  int c = blockIdx.x, k = threadIdx.x;
  Wct[(size_t)c * 256 + k] = f2bf(Whe[(size_t)k * 256 + c]);
}

// Wct rows 256..1023: (Whe_h @ Whh)^T computed in fp32, one bf16 rounding
__global__ __launch_bounds__(256) void wct_b_k(const float* __restrict__ Whe,
                                               const float* __restrict__ Whh,
                                               ushort_t* __restrict__ Wct) {
  int c = blockIdx.x;   // 0..767 (gh column)
  int k = threadIdx.x;  // h feature
  float acc = 0.f;
  for (int j = 0; j < 256; j++)
    acc += Whe[(size_t)k * 256 + j] * Whh[(size_t)j * 768 + c];
  Wct[(size_t)(256 + c) * 256 + k] = f2bf(acc);
}

__global__ void bsum_k(const float* __restrict__ bih, const float* __restrict__ bhh,
                       float* __restrict__ bs) {
  int i = blockIdx.x * 256 + threadIdx.x;
  if (i < 768) bs[i] = bih[i] + bhh[i];
}

// AE[m=t*B+b][k2] = actions[b,t,:] @ Wae + bae   (fp32)
__global__ __launch_bounds__(256) void ae_k(const float* __restrict__ actions,
                                            const float* __restrict__ Wae,
                                            const float* __restrict__ bae,
                                            float* __restrict__ AE) {
  int idx = blockIdx.x * 256 + threadIdx.x;
  int m = idx >> 4, k2 = idx & 15;
  int t = m >> 8, b = m & 255;
  const float* arow = actions + ((size_t)b * T_ + t) * A_;
  float acc = bae[k2];
  for (int k = 0; k < 16; k++) acc += arow[k] * Wae[k * 16 + k2];
  AE[(size_t)m * 16 + k2] = acc;
}

// Penc[t][b][j] = bhe[j] + (t>0 ? AE[t-1,b,:] @ Whe[256:272,:] : 0)
// writes fp32 into C0 cols [0:256) and bf16 copy to Pencb
__global__ __launch_bounds__(256) void penc_k(const float* __restrict__ AE,
                                              const float* __restrict__ Whe,
                                              const float* __restrict__ bhe,
                                              float* __restrict__ C0,
                                              ushort_t* __restrict__ Pencb) {
  int m = blockIdx.x;          // t*B + b
  int j = threadIdx.x;         // 0..255
  __shared__ float a[16];
  if (threadIdx.x < 16)
    a[threadIdx.x] = (m >= B_) ? AE[(size_t)(m - B_) * 16 + threadIdx.x] : 0.f;
  __syncthreads();
  float acc = bhe[j];
  if (m >= B_) {
    for (int k = 0; k < 16; k++) acc += a[k] * Whe[(size_t)(256 + k) * 256 + j];
  }
  C0[(size_t)m * 1024 + j] = acc;
  Pencb[(size_t)m * 256 + j] = f2bf(acc);
}

// per-t BatchNorm (training, biased var) + ELU, fp32 in -> bf16 out
__global__ __launch_bounds__(512) void bn_elu_k(const float* __restrict__ Y,
                                                const float* __restrict__ g,
                                                const float* __restrict__ be,
                                                ushort_t* __restrict__ Xb) {
  int t = blockIdx.x, f = threadIdx.x;   // 512 features
  const float* base = Y + (size_t)t * B_ * H1_;
  float s = 0.f, ss = 0.f;
  for (int b = 0; b < B_; b++) {
    float v = base[(size_t)b * H1_ + f];
    s += v; ss += v * v;
  }
  float mu  = s * (1.f / B_);
  float var = ss * (1.f / B_) - mu * mu;
  float inv = 1.f / sqrtf(var + 1e-5f);
  float sc = g[f] * inv, sh = be[f] - mu * sc;
  ushort_t* ob = Xb + (size_t)t * B_ * H1_;
  for (int b = 0; b < B_; b++) {
    float v = base[(size_t)b * H1_ + f] * sc + sh;
    float e = v > 0.f ? v : (expf(v) - 1.f);
    ob[(size_t)b * H1_ + f] = f2bf(e);
  }
}

__global__ __launch_bounds__(256) void cast_k(const float* __restrict__ in,
                                              ushort_t* __restrict__ out, long n) {
  long i = (long)blockIdx.x * 256 + threadIdx.x;
  if (i < n) out[i] = f2bf(in[i]);
}

// ---------------- bf16 MFMA GEMM: C[m,n] (+)= A[m,:] . Bt[n,:] + bias[n] ----------------
// A: bf16 [M,lda], Bt: bf16 [N,ldb] (B transposed), C: fp32 (ldc), 64x64 tile, BK=32.
// grid = (M/64, N/64), 256 threads (4 waves in 2x2).
__global__ __launch_bounds__(256) void gemm_bt_k(const ushort_t* __restrict__ A, int lda,
                                                 const ushort_t* __restrict__ Bt, int ldb,
                                                 float* __restrict__ C, int ldc,
                                                 const float* __restrict__ bias,
                                                 int K, int accum) {
  __shared__ __align__(16) ushort_t As[64][40];  // +8 pad: 2-way banks (free)
  __shared__ __align__(16) ushort_t Bs[64][40];
  int tid = threadIdx.x;
  int wave = tid >> 6, lane = tid & 63;
  int q = lane >> 4, l15 = lane & 15;
  int wr = wave >> 1, wc = wave & 1;
  int m0 = blockIdx.x * 64, n0 = blockIdx.y * 64;
  f32x4 acc[2][2] = {};
  int r = tid >> 2, seg = tid & 3;
  const ushort_t* aSrc = A + (size_t)(m0 + r) * lda + seg * 8;
  const ushort_t* bSrc = Bt + (size_t)(n0 + r) * ldb + seg * 8;
  for (int k0 = 0; k0 < K; k0 += 32) {
    *(short8*)&As[r][seg * 8] = *(const short8*)(aSrc + k0);
    *(short8*)&Bs[r][seg * 8] = *(const short8*)(bSrc + k0);
    __syncthreads();
    frag8 a0, a1, b0, b1;
    a0.s = *(const short8*)&As[wr * 32 + l15][q * 8];
    a1.s = *(const short8*)&As[wr * 32 + 16 + l15][q * 8];
    b0.s = *(const short8*)&Bs[wc * 32 + l15][q * 8];
    b1.s = *(const short8*)&Bs[wc * 32 + 16 + l15][q * 8];
    acc[0][0] = __builtin_amdgcn_mfma_f32_16x16x32_bf16(a0.b, b0.b, acc[0][0], 0, 0, 0);
    acc[0][1] = __builtin_amdgcn_mfma_f32_16x16x32_bf16(a0.b, b1.b, acc[0][1], 0, 0, 0);
    acc[1][0] = __builtin_amdgcn_mfma_f32_16x16x32_bf16(a1.b, b0.b, acc[1][0], 0, 0, 0);
    acc[1][1] = __builtin_amdgcn_mfma_f32_16x16x32_bf16(a1.b, b1.b, acc[1][1], 0, 0, 0);
    __syncthreads();
  }
  for (int at = 0; at < 2; at++)
    for (int bt = 0; bt < 2; bt++) {
      int mb = m0 + wr * 32 + at * 16 + q * 4;       // C/D: row = quad*4+i
      int n  = n0 + wc * 32 + bt * 16 + l15;         //      col = lane&15
      float bv = bias ? bias[n] : 0.f;
      for (int i = 0; i < 4; i++) {
        size_t idx = (size_t)(mb + i) * ldc + n;
        float v = acc[at][bt][i] + bv;
        if (accum) v += C[idx];
        C[idx] = v;
      }
    }
}

// ---------------- communication-free GRU recurrence (v4) ----------------
// Row partition: block k owns batch rows [16k,16k+16) for ALL 128 steps; no
// inter-block communication. v3 post-mortem: compiler pins VGPR at 128 (its
// 4-waves/EU target) and demotes any weight array that doesn't fit -> design
// FOR the 128-VGPR point and buy latency-hiding with TLP instead:
//   16 waves (1024 thr, 4 waves/SIMD). Wave w owns h-cols [16w,16w+16),
//   ALL 4 gates for those cols (gate fusion stays in-lane).
//   - hn weights (128KB)    -> LDS-resident [256][264] (<=2-way banks, free)
//   - henc weights          -> VGPR-stationary, only 32 VGPR/wave (8 frags)
//   - r+z weights (256KB)   -> streamed from L2 each step (irreducible)
//   - C0/INN (20 dwords)    -> prefetched at step top, consumed in epilogue
// VGPR: 32 wts + 16 acc + 20 prefetch + ~40 frags/stream/addr ~= 110 < 128.
// Floor: (256KB wts + 80KB C0)/64B/cy ~= 5250cy ~= 2.2us/step.
__global__ __launch_bounds__(1024, 4) void gru_rows_k(
    const ushort_t* __restrict__ Wct,
    const float* __restrict__ C0,
    const float* __restrict__ INN,
    float* __restrict__ outF) {
  __shared__ __align__(16) ushort_t Wn[256][264];       // hn weights (135KB)
  __shared__ __align__(16) ushort_t hbuf[2][16][264];   // h double-buffer (17KB)
  const int tid = threadIdx.x;
  const int w = tid >> 6, lane = tid & 63;
  const int q = lane >> 4, l15 = lane & 15;
  const int r0 = blockIdx.x * 16;          // batch rows [r0, r0+16)
  const int col0 = w * 16;                 // wave's h-col base (16 cols)

  // zero h(0) (both buffers, incl. pad)
  {
    unsigned* hz = (unsigned*)hbuf;
    for (int i = tid; i < 2 * 16 * 264 / 2; i += 1024) hz[i] = 0u;
  }
  // stage hn weights (Wct rows 768..1023) into LDS
  for (int i = tid; i < 256 * 32; i += 1024) {
    int rr = i >> 5, ss = i & 31;
    *(short8*)&Wn[rr][ss * 8] = *(const short8*)(Wct + (size_t)(768 + rr) * 256 + ss * 8);
  }

  // VGPR-stationary henc weights (Wct rows 0..255): 8 kc frags = 32 VGPR
  frag8 whe_s[8];
  {
    const ushort_t* p = Wct + (size_t)(col0 + l15) * 256 + q * 8;
#pragma unroll
    for (int kc = 0; kc < 8; kc++) whe_s[kc].s = *(const short8*)(p + kc * 32);
  }
  // streamed bases: r (rows 256+), z (rows 512+)
  const ushort_t* wr_ = Wct + (size_t)(256 + col0 + l15) * 256 + q * 8;
  const ushort_t* wz_ = Wct + (size_t)(512 + col0 + l15) * 256 + q * 8;

  __syncthreads();

  const int hc = col0 + l15;               // this lane's h-col

  for (int t = 0; t < T_; t++) {
    const int cur = t & 1, nxt = cur ^ 1;
    const float* c0t  = C0  + ((size_t)t * B_ + r0) * 1024;
    const float* innt = INN + ((size_t)t * B_ + r0) * 256;

    // prefetch ALL per-step C0/INN (20 dwords/lane), consumed in epilogue
    float c0g[4][4], innv[4];
#pragma unroll
    for (int i = 0; i < 4; i++) {
      int row = q * 4 + i;
      const float* rp = c0t + (size_t)row * 1024 + hc;
      c0g[0][i] = rp[0];
      c0g[1][i] = rp[256];
      c0g[2][i] = rp[512];
      c0g[3][i] = rp[768];
      innv[i] = innt[(size_t)row * 256 + hc];
    }

    f32x4 acc[4] = {};   // [gate]
#pragma unroll
    for (int kc = 0; kc < 8; kc++) {
      frag8 a; a.s = *(const short8*)&hbuf[cur][l15][kc * 32 + q * 8];
      frag8 br_, bz_, bn_;
      br_.s = *(const short8*)(wr_ + kc * 32);
      bz_.s = *(const short8*)(wz_ + kc * 32);
      bn_.s = *(const short8*)&Wn[hc][kc * 32 + q * 8];
      acc[0] = __builtin_amdgcn_mfma_f32_16x16x32_bf16(a.b, whe_s[kc].b, acc[0], 0, 0, 0);
      acc[1] = __builtin_amdgcn_mfma_f32_16x16x32_bf16(a.b, br_.b, acc[1], 0, 0, 0);
      acc[2] = __builtin_amdgcn_mfma_f32_16x16x32_bf16(a.b, bz_.b, acc[2], 0, 0, 0);
      acc[3] = __builtin_amdgcn_mfma_f32_16x16x32_bf16(a.b, bn_.b, acc[3], 0, 0, 0);
    }

    // epilogue: gate math on prefetched values, write h(t+1) to LDS
#pragma unroll
    for (int i = 0; i < 4; i++) {
      int row = q * 4 + i;
      float henc = acc[0][i] + c0g[0][i];
      float rp   = acc[1][i] + c0g[1][i];
      float zp   = acc[2][i] + c0g[2][i];
      float hn   = acc[3][i] + c0g[3][i];
      float rg = 1.f / (1.f + expf(-rp));
      float zg = 1.f / (1.f + expf(-zp));
      float ng = tanhf(innv[i] + rg * hn);
      float hv = (1.f - zg) * ng + zg * henc;
      if (t < T_ - 1) hbuf[nxt][row][hc] = f2bf(hv);
      else            outF[(size_t)(r0 + row) * 256 + hc] = hv;
    }
    __syncthreads();   // h(t+1) complete before any wave reads it next step
  }
}

// ---------------- launch ----------------
extern "C" void kernel_launch(void* const* d_in, const int* in_sizes, int n_in,
                              void* d_out, int out_size, void* d_ws, size_t ws_size,
                              hipStream_t stream) {
  const float* obs     = (const float*)d_in[0];
  const float* actions = (const float*)d_in[1];
  const float* W1  = (const float*)d_in[2];
  const float* b1  = (const float*)d_in[3];
  const float* g1  = (const float*)d_in[4];
  const float* be1 = (const float*)d_in[5];
  const float* W2  = (const float*)d_in[6];
  const float* b2  = (const float*)d_in[7];
  const float* g2  = (const float*)d_in[8];
  const float* be2 = (const float*)d_in[9];
  const float* W3  = (const float*)d_in[10];
  const float* b3  = (const float*)d_in[11];
  const float* Wih = (const float*)d_in[12];
  const float* bih = (const float*)d_in[13];
  const float* Whh = (const float*)d_in[14];
  const float* bhh = (const float*)d_in[15];
  const float* Whe = (const float*)d_in[16];
  const float* bhe = (const float*)d_in[17];
  const float* Wae = (const float*)d_in[18];
  const float* bae = (const float*)d_in[19];

  char* ws = (char*)d_ws;
  float*    C0    = (float*)(ws + OFF_C0);
  ushort_t* obsb  = (ushort_t*)(ws + OFF_OBSB);
  float*    Y     = (float*)(ws + OFF_Y);
  float*    Yg    = (float*)(ws + OFF_YG);
  ushort_t* XG    = (ushort_t*)(ws + OFF_XG);
  ushort_t* Pencb = (ushort_t*)(ws + OFF_PENCB);
  ushort_t* Xb    = (ushort_t*)(ws + OFF_XB);
  float*    INN   = (float*)(ws + OFF_INN);
  float*    AE    = (float*)(ws + OFF_AE);
  ushort_t* W1t   = (ushort_t*)(ws + OFF_W1T);
  ushort_t* W2t   = (ushort_t*)(ws + OFF_W2T);
  ushort_t* W3t   = (ushort_t*)(ws + OFF_W3T);
  ushort_t* Wiht  = (ushort_t*)(ws + OFF_WIHT);
  ushort_t* Whht  = (ushort_t*)(ws + OFF_WHHT);
  ushort_t* Wct   = (ushort_t*)(ws + OFF_WCT);
  float*    bsum  = (float*)(ws + OFF_BSUM);
  float*    outF  = (float*)d_out;

  // prologue: casts / transposes / small precomputes
  cast_obs_k<<<MT_, 256, 0, stream>>>(obs, obsb);
  transpose_cast_k<<<dim3(16, 32), 256, 0, stream>>>(W1, W1t, 1024, 512);
  transpose_cast_k<<<dim3(16, 16), 256, 0, stream>>>(W2, W2t, 512, 512);
  transpose_cast_k<<<dim3(8, 16),  256, 0, stream>>>(W3, W3t, 512, 256);
  transpose_cast_k<<<dim3(24, 8),  256, 0, stream>>>(Wih, Wiht, 256, 768);
  transpose_cast_k<<<dim3(24, 8),  256, 0, stream>>>(Whh, Whht, 256, 768);
  wct_a_k<<<256, 256, 0, stream>>>(Whe, Wct);
  wct_b_k<<<768, 256, 0, stream>>>(Whe, Whh, Wct);
  bsum_k<<<3, 256, 0, stream>>>(bih, bhh, bsum);
  ae_k<<<MT_ * 16 / 256, 256, 0, stream>>>(actions, Wae, bae, AE);

  // MLP (parallel over all T*B rows, t-major)
  gemm_bt_k<<<dim3(512, 8), 256, 0, stream>>>(obsb, 1024, W1t, 1024, Y, 512, b1, 1024, 0);
  bn_elu_k<<<T_, 512, 0, stream>>>(Y, g1, be1, Xb);
  gemm_bt_k<<<dim3(512, 8), 256, 0, stream>>>(Xb, 512, W2t, 512, Y, 512, b2, 512, 0);
  bn_elu_k<<<T_, 512, 0, stream>>>(Y, g2, be2, Xb);
  gemm_bt_k<<<dim3(512, 4), 256, 0, stream>>>(Xb, 512, W3t, 512, Yg, 256, b3, 512, 0);
  cast_k<<<MT_ * 256 / 256, 256, 0, stream>>>(Yg, XG, (long)MT_ * 256);

  // per-step constants: Penc -> C0[:,0:256); r/z pre -> C0[:,256:768); hn0 -> C0[:,768:1024); INN
  penc_k<<<MT_, 256, 0, stream>>>(AE, Whe, bhe, C0, Pencb);
  gemm_bt_k<<<dim3(512, 8), 256, 0, stream>>>(XG, 256, Wiht, 256, C0 + 256, 1024, bsum, 256, 0);
  gemm_bt_k<<<dim3(512, 8), 256, 0, stream>>>(Pencb, 256, Whht, 256, C0 + 256, 1024, nullptr, 256, 1);
  gemm_bt_k<<<dim3(512, 4), 256, 0, stream>>>(Pencb, 256, Whht + 512 * 256, 256, C0 + 768, 1024, bhh + 512, 256, 0);
  gemm_bt_k<<<dim3(512, 4), 256, 0, stream>>>(XG, 256, Wiht + 512 * 256, 256, INN, 256, bih + 512, 256, 0);

  // sequential recurrence: 16 independent blocks, each owns 16 batch rows for
  // all 128 steps; h stays in LDS; no inter-block sync of any kind.
  gru_rows_k<<<16, 1024, 0, stream>>>(Wct, C0, INN, outF);
}